// Round 1
// baseline (360.433 us; speedup 1.0000x reference)
//
#include <hip/hip_runtime.h>
#include <hip/hip_bf16.h>

// Problem: out[n] = sum_m coefs[m] * exp(-||L_m^T (x_n - c_m)||^2)
//   coefs[m] = softmax(w)[m] * |det(L_m)|   (since A = L L^T => sqrt(det A) = |det L|)
// N=131072 points, M=32 centers, D=32 dims. All f32.
//
// Strategy (round 1): correct, VALU-optimized f32 version.
//  - gmm_pre: 32 blocks, each does LU(32x32) for |det|, C2[m][k] = (L_m^T c_m)_k,
//    coefs[m]. ~2-5 us.
//  - gmm_main: 1 thread = 1 point. x in 32 VGPRs. Loop m; inner loop over d with
//    L-row at wave-uniform address -> s_load into SGPRs, v_fmac with SGPR operand.
//    32 independent z[k] accumulation chains -> full ILP. ~1.07 VALU instr / FMA.

#define D 32
#define M 32

__global__ __launch_bounds__(64) void gmm_pre(
    const float* __restrict__ centers, const float* __restrict__ L,
    const float* __restrict__ weights, float* __restrict__ C2,
    float* __restrict__ coefs) {
  __shared__ float U[D][D + 1];
  const int m = blockIdx.x;
  const int t = threadIdx.x;
  const float* Lm = L + m * (D * D);

  if (t < D) {
    // stage L_m rows into LDS for LU
    for (int k = 0; k < D; ++k) U[t][k] = Lm[t * D + k];
    // C2[m][t] = sum_d c[m][d] * L[m][d][t]
    float acc = 0.f;
    for (int d = 0; d < D; ++d) acc = fmaf(centers[m * D + d], Lm[d * D + t], acc);
    C2[m * D + t] = acc;
  }
  __syncthreads();

  // LU without pivoting (L = I + 0.05*noise -> diagonally dominant enough)
  for (int p = 0; p < D - 1; ++p) {
    if (t > p && t < D) {
      float f = U[t][p] / U[p][p];
      for (int k = p; k < D; ++k) U[t][k] -= f * U[p][k];
    }
    __syncthreads();
  }

  if (t == 0) {
    float det = 1.f;
    for (int i = 0; i < D; ++i) det *= U[i][i];
    float mx = -1e30f;
    for (int j = 0; j < M; ++j) mx = fmaxf(mx, weights[j]);
    float s = 0.f;
    for (int j = 0; j < M; ++j) s += __expf(weights[j] - mx);
    coefs[m] = (__expf(weights[m] - mx) / s) * fabsf(det);
  }
}

__global__ __launch_bounds__(256) void gmm_main(
    const float* __restrict__ points, const float* __restrict__ L,
    const float* __restrict__ C2, const float* __restrict__ coefs,
    float* __restrict__ out, int N) {
  const int n = blockIdx.x * blockDim.x + threadIdx.x;
  if (n >= N) return;

  // load point into registers (coalesced float4)
  float x[D];
  const float4* p4 = reinterpret_cast<const float4*>(points + (size_t)n * D);
#pragma unroll
  for (int i = 0; i < D / 4; ++i) {
    float4 v = p4[i];
    x[4 * i + 0] = v.x; x[4 * i + 1] = v.y;
    x[4 * i + 2] = v.z; x[4 * i + 3] = v.w;
  }

  float result = 0.f;
#pragma unroll 1
  for (int m = 0; m < M; ++m) {
    const float* __restrict__ Lm = L + m * (D * D);   // wave-uniform
    const float* __restrict__ c2 = C2 + m * D;        // wave-uniform

    // z[k] = -(L^T c)_k, then z += L^T x  => z = L^T (x - c)
    float z[D];
#pragma unroll
    for (int k = 0; k < D; ++k) z[k] = -c2[k];

#pragma unroll
    for (int d = 0; d < D; ++d) {
      const float xd = x[d];
#pragma unroll
      for (int k = 0; k < D; ++k) {
        z[k] = fmaf(xd, Lm[d * D + k], z[k]);  // SGPR (L) x VGPR (x) -> 32 indep chains
      }
    }

    // dist = sum z^2 with 4 partial chains
    float d0 = 0.f, d1 = 0.f, d2 = 0.f, d3 = 0.f;
#pragma unroll
    for (int k = 0; k < D; k += 4) {
      d0 = fmaf(z[k + 0], z[k + 0], d0);
      d1 = fmaf(z[k + 1], z[k + 1], d1);
      d2 = fmaf(z[k + 2], z[k + 2], d2);
      d3 = fmaf(z[k + 3], z[k + 3], d3);
    }
    const float dist = (d0 + d1) + (d2 + d3);
    result = fmaf(coefs[m], __expf(-dist), result);
  }
  out[n] = result;
}

extern "C" void kernel_launch(void* const* d_in, const int* in_sizes, int n_in,
                              void* d_out, int out_size, void* d_ws, size_t ws_size,
                              hipStream_t stream) {
  const float* points  = (const float*)d_in[0];
  const float* centers = (const float*)d_in[1];
  const float* L       = (const float*)d_in[2];
  const float* weights = (const float*)d_in[3];
  float* out = (float*)d_out;
  const int N = in_sizes[0] / D;

  float* C2    = (float*)d_ws;          // 32*32 f32
  float* coefs = C2 + M * D;            // 32 f32

  gmm_pre<<<M, 64, 0, stream>>>(centers, L, weights, C2, coefs);
  gmm_main<<<(N + 255) / 256, 256, 0, stream>>>(points, L, C2, coefs, out, N);
}

// Round 2
// 122.893 us; speedup vs baseline: 2.9329x; 2.9329x over previous
//
#include <hip/hip_runtime.h>
#include <hip/hip_bf16.h>

// out[n] = sum_m coefs[m] * exp(-||L_m^T (x_n - c_m)||^2),  coefs[m]=softmax(w)[m]*|det L_m|
// N=131072, M=32, D=32, f32.
//
// Round 2: MFMA path. Z = X*L - (c*L) per m via mfma_f32_16x16x32_bf16 (K=32=D in ONE mfma).
// f32 accuracy via Dekker split: x=xh+xl, L=Lh+Ll; Z ~= xh*Lh + xl*Lh + xh*Ll (3 MFMAs).
// dist = row-sum of Z^2 via DPP row_ror butterfly (VALU pipe, not DS).
// B-fragments (Lh/Ll) pre-split in gmm_pre into exact fragment layout -> 1 dwordx4 load each.

#define D 32
#define M 32
#define WT 2  // point-tiles (of 16) per wave

typedef __attribute__((ext_vector_type(8))) short short8;
typedef __attribute__((ext_vector_type(4))) float f32x4;

__device__ __forceinline__ unsigned short f2bf_rne(float f) {
  unsigned int u = __float_as_uint(f);
  return (unsigned short)((u + 0x7FFFu + ((u >> 16) & 1u)) >> 16);
}

// x + ror16(x) within each 16-lane DPP row; ctrl: 0x128=ror:8 0x124=ror:4 0x122=ror:2 0x121=ror:1
#define ROR_ADD(x, ctrl) \
  ((x) + __int_as_float(__builtin_amdgcn_mov_dpp(__float_as_int(x), (ctrl), 0xf, 0xf, true)))

__global__ __launch_bounds__(64) void gmm_pre(
    const float* __restrict__ centers, const float* __restrict__ L,
    const float* __restrict__ weights,
    float* __restrict__ C2f, float* __restrict__ coefs,
    unsigned short* __restrict__ LH, unsigned short* __restrict__ LL) {
  __shared__ float U[D][D + 1];
  const int m = blockIdx.x;
  const int t = threadIdx.x;
  const float* Lm = L + m * (D * D);

  if (t < D) {
    for (int k = 0; k < D; ++k) U[t][k] = Lm[t * D + k];
    float acc = 0.f;
    for (int d = 0; d < D; ++d) acc = fmaf(centers[m * D + d], Lm[d * D + t], acc);
    C2f[m * D + t] = acc;  // (L^T c)_t
  }

  // B-fragment split, layout [m][ktile][lane][j] (j = k-slot within lane)
  {
    const int col = t & 15;
    const int dbase = 8 * (t >> 4);
    for (int kt = 0; kt < 2; ++kt) {
      for (int j = 0; j < 8; ++j) {
        const int d = dbase + j;
        const int k = kt * 16 + col;
        float v = Lm[d * D + k];
        unsigned int hi = __float_as_uint(v) & 0xFFFF0000u;
        float lo = v - __uint_as_float(hi);
        size_t off = (((size_t)(m * 2 + kt)) * 64 + t) * 8 + j;
        LH[off] = (unsigned short)(hi >> 16);
        LL[off] = f2bf_rne(lo);
      }
    }
  }
  __syncthreads();

  // LU (no pivot; L ~ I + 0.05*noise) for |det|
  for (int p = 0; p < D - 1; ++p) {
    if (t > p && t < D) {
      float f = U[t][p] / U[p][p];
      for (int k = p; k < D; ++k) U[t][k] -= f * U[p][k];
    }
    __syncthreads();
  }
  if (t == 0) {
    float det = 1.f;
    for (int i = 0; i < D; ++i) det *= U[i][i];
    float mx = -1e30f;
    for (int j = 0; j < M; ++j) mx = fmaxf(mx, weights[j]);
    float s = 0.f;
    for (int j = 0; j < M; ++j) s += __expf(weights[j] - mx);
    coefs[m] = (__expf(weights[m] - mx) / s) * fabsf(det);
  }
}

__global__ __launch_bounds__(256) void gmm_main(
    const float* __restrict__ points,
    const float* __restrict__ C2f, const float* __restrict__ coefs,
    const unsigned short* __restrict__ LH, const unsigned short* __restrict__ LL,
    float* __restrict__ out, int N) {
  const int lane = threadIdx.x & 63;
  const int wave = threadIdx.x >> 6;
  const int col = lane & 15;   // A-row (point) / B-col (k) / D-col (k)
  const int g = lane >> 4;     // lane group -> d-slot base 8*g; D-rows 4*g..4*g+3
  const int tileBase = (blockIdx.x * 4 + wave) * (WT * 16);
  if (tileBase >= N) return;

  // ---- load X tiles, Dekker-split into bf16 hi/lo fragments ----
  short8 xh[WT], xl[WT];
#pragma unroll
  for (int t = 0; t < WT; ++t) {
    const float* p = points + (size_t)(tileBase + t * 16 + col) * D + 8 * g;
    float4 a = *reinterpret_cast<const float4*>(p);
    float4 b = *reinterpret_cast<const float4*>(p + 4);
    float v[8] = {a.x, a.y, a.z, a.w, b.x, b.y, b.z, b.w};
    unsigned int hiu[8];
    unsigned int lou[8];
#pragma unroll
    for (int j = 0; j < 8; ++j) {
      unsigned int u = __float_as_uint(v[j]);
      hiu[j] = u & 0xFFFF0000u;                       // hi = trunc-bf16 (exact split)
      lou[j] = __float_as_uint(v[j] - __uint_as_float(hiu[j]));
    }
    union { short8 s; unsigned int w[4]; } H, Lo;
#pragma unroll
    for (int jj = 0; jj < 4; ++jj) {
      // pack two bf16 (top halves) into one dword: [e0.hi16 | e1.hi16]
      H.w[jj]  = __builtin_amdgcn_perm(hiu[2 * jj + 1], hiu[2 * jj], 0x07060302);
      Lo.w[jj] = __builtin_amdgcn_perm(lou[2 * jj + 1], lou[2 * jj], 0x07060302);
    }
    xh[t] = H.s;
    xl[t] = Lo.s;
  }

  f32x4 result[WT];
#pragma unroll
  for (int t = 0; t < WT; ++t) result[t] = (f32x4){0.f, 0.f, 0.f, 0.f};

#pragma unroll 2
  for (int m = 0; m < M; ++m) {
    const short8* bhp = reinterpret_cast<const short8*>(LH + (size_t)(m * 2) * 64 * 8);
    const short8* blp = reinterpret_cast<const short8*>(LL + (size_t)(m * 2) * 64 * 8);
    short8 bh0 = bhp[lane];
    short8 bh1 = bhp[64 + lane];
    short8 bl0 = blp[lane];
    short8 bl1 = blp[64 + lane];
    const float c0 = C2f[m * D + col];
    const float c1 = C2f[m * D + 16 + col];
    const float coef = coefs[m];

#pragma unroll
    for (int t = 0; t < WT; ++t) {
      f32x4 acc0 = (f32x4){-c0, -c0, -c0, -c0};  // bias: Z = X*L - c^T L
      f32x4 acc1 = (f32x4){-c1, -c1, -c1, -c1};
      acc0 = __builtin_amdgcn_mfma_f32_16x16x32_bf16(xh[t], bh0, acc0, 0, 0, 0);
      acc0 = __builtin_amdgcn_mfma_f32_16x16x32_bf16(xl[t], bh0, acc0, 0, 0, 0);
      acc0 = __builtin_amdgcn_mfma_f32_16x16x32_bf16(xh[t], bl0, acc0, 0, 0, 0);
      acc1 = __builtin_amdgcn_mfma_f32_16x16x32_bf16(xh[t], bh1, acc1, 0, 0, 0);
      acc1 = __builtin_amdgcn_mfma_f32_16x16x32_bf16(xl[t], bh1, acc1, 0, 0, 0);
      acc1 = __builtin_amdgcn_mfma_f32_16x16x32_bf16(xh[t], bl1, acc1, 0, 0, 0);

#pragma unroll
      for (int r = 0; r < 4; ++r) {
        float s = fmaf(acc0[r], acc0[r], acc1[r] * acc1[r]);  // z^2 (this lane's 2 cols)
        s = ROR_ADD(s, 0x128);  // sum across 16 cols (k) via DPP row rotations
        s = ROR_ADD(s, 0x124);
        s = ROR_ADD(s, 0x122);
        s = ROR_ADD(s, 0x121);
        result[t][r] = fmaf(coef, __expf(-s), result[t][r]);
      }
    }
  }

  // D row = 4*g + r; all 16 lanes of a group hold identical sums -> lane col==0 writes
  if (col == 0) {
#pragma unroll
    for (int t = 0; t < WT; ++t)
#pragma unroll
      for (int r = 0; r < 4; ++r)
        out[tileBase + t * 16 + 4 * g + r] = result[t][r];
  }
}

extern "C" void kernel_launch(void* const* d_in, const int* in_sizes, int n_in,
                              void* d_out, int out_size, void* d_ws, size_t ws_size,
                              hipStream_t stream) {
  const float* points  = (const float*)d_in[0];
  const float* centers = (const float*)d_in[1];
  const float* L       = (const float*)d_in[2];
  const float* weights = (const float*)d_in[3];
  float* out = (float*)d_out;
  const int N = in_sizes[0] / D;

  char* ws = (char*)d_ws;
  float* C2f            = (float*)ws;                       // 32*32 f32 = 4096 B
  float* coefs          = (float*)(ws + 4096);              // 128 B
  unsigned short* LHf   = (unsigned short*)(ws + 4352);     // 32*2*64*8*2 = 65536 B
  unsigned short* LLf   = (unsigned short*)(ws + 4352 + 65536);

  gmm_pre<<<M, 64, 0, stream>>>(centers, L, weights, C2f, coefs, LHf, LLf);

  const int ptsPerBlock = 4 * WT * 16;  // 4 waves * WT tiles * 16
  gmm_main<<<(N + ptsPerBlock - 1) / ptsPerBlock, 256, 0, stream>>>(
      points, C2f, coefs, LHf, LLf, out, N);
}

// Round 3
// 122.050 us; speedup vs baseline: 2.9532x; 1.0069x over previous
//
#include <hip/hip_runtime.h>
#include <hip/hip_bf16.h>

// out[n] = sum_m coefs[m] * exp(-||L_m^T (x_n - c_m)||^2),  coefs[m]=softmax(w)[m]*|det L_m|
// N=131072, M=32, D=32, f32.
//
// Round 3: MFMA path (3x bf16 Dekker-split MFMAs per acc, verified round 2) with a
// restructured epilogue:
//  - L pre-scaled by sqrt(log2 e) so dist is in log2 units -> single exp2f, no mul.
//  - lc[m]=log2(coef) folded additively.
//  - reduction: 2 ror-adds (coset partials) + 3 cndmask lane-transpose + quad_perm
//    butterfly -> ONE exp2 per (m,tile) instead of 4 redundant __expf.
//  - bias -(sL)^T c pre-negated, per-lane float2 table (1 dwordx2 per m).
//  - #pragma unroll 4 on m-loop for VMEM pipelining.

#define D 32
#define M 32
#define WT 2  // point-tiles (of 16) per wave

typedef __attribute__((ext_vector_type(8))) short short8;
typedef __attribute__((ext_vector_type(4))) float f32x4;

__device__ __forceinline__ unsigned short f2bf_rne(float f) {
  unsigned int u = __float_as_uint(f);
  return (unsigned short)((u + 0x7FFFu + ((u >> 16) & 1u)) >> 16);
}

// x + dpp(x); 0x128=row_ror:8 0x124=row_ror:4 (coset sums: direction-invariant)
// 0xB1=quad_perm[1,0,3,2] (xor1) 0x4E=quad_perm[2,3,0,1] (xor2)
#define DPP_ADD(x, ctrl) \
  ((x) + __int_as_float(__builtin_amdgcn_mov_dpp(__float_as_int(x), (ctrl), 0xf, 0xf, true)))

#define SCL 1.2011224087864498f  // sqrt(log2(e))

__global__ __launch_bounds__(64) void gmm_pre(
    const float* __restrict__ centers, const float* __restrict__ L,
    const float* __restrict__ weights,
    float2* __restrict__ CN, float* __restrict__ LC,
    unsigned short* __restrict__ LH, unsigned short* __restrict__ LL) {
  __shared__ float U[D][D + 1];
  __shared__ float C2s[D];
  const int m = blockIdx.x;
  const int t = threadIdx.x;
  const float* Lm = L + m * (D * D);

  if (t < D) {
    for (int k = 0; k < D; ++k) U[t][k] = Lm[t * D + k];
    float acc = 0.f;
    for (int d = 0; d < D; ++d) acc = fmaf(centers[m * D + d], Lm[d * D + t], acc);
    C2s[t] = acc;  // (L^T c)_t, unscaled
  }

  // B-fragment split of (SCL * L), layout [m][ktile][lane][j]
  {
    const int col = t & 15;
    const int dbase = 8 * (t >> 4);
    for (int kt = 0; kt < 2; ++kt) {
      for (int j = 0; j < 8; ++j) {
        const int d = dbase + j;
        const int k = kt * 16 + col;
        float v = Lm[d * D + k] * SCL;
        unsigned int hi = __float_as_uint(v) & 0xFFFF0000u;
        float lo = v - __uint_as_float(hi);
        size_t off = (((size_t)(m * 2 + kt)) * 64 + t) * 8 + j;
        LH[off] = (unsigned short)(hi >> 16);
        LL[off] = f2bf_rne(lo);
      }
    }
  }
  __syncthreads();

  // per-lane bias table: acc init = -(SCL*L)^T c for this lane's k-columns
  CN[m * 64 + t] = make_float2(-SCL * C2s[t & 15], -SCL * C2s[16 + (t & 15)]);

  // LU (no pivot; L ~ I + 0.05*noise) for |det|
  for (int p = 0; p < D - 1; ++p) {
    if (t > p && t < D) {
      float f = U[t][p] / U[p][p];
      for (int k = p; k < D; ++k) U[t][k] -= f * U[p][k];
    }
    __syncthreads();
  }
  if (t == 0) {
    float det = 1.f;
    for (int i = 0; i < D; ++i) det *= U[i][i];
    float mx = -1e30f;
    for (int j = 0; j < M; ++j) mx = fmaxf(mx, weights[j]);
    float s = 0.f;
    for (int j = 0; j < M; ++j) s += __expf(weights[j] - mx);
    float coef = (__expf(weights[m] - mx) / s) * fabsf(det);
    LC[m] = log2f(coef);
  }
}

__global__ __launch_bounds__(256) void gmm_main(
    const float* __restrict__ points,
    const float2* __restrict__ CN, const float* __restrict__ LC,
    const unsigned short* __restrict__ LH, const unsigned short* __restrict__ LL,
    float* __restrict__ out, int N) {
  const int lane = threadIdx.x & 63;
  const int wave = threadIdx.x >> 6;
  const int col = lane & 15;   // A-row (point) / B-col (k)
  const int g = lane >> 4;     // A k-slot base 8g; D rows 4g..4g+3
  const int tileBase = (blockIdx.x * 4 + wave) * (WT * 16);
  if (tileBase >= N) return;

  // lane-transpose selectors: want lane i to hold partial(coset i&3, r=(i>>2)&3)
  const bool b0 = (lane >> 2) & 1;
  const bool b1 = (lane >> 2) & 2;

  // ---- load X tiles, Dekker-split into bf16 hi/lo fragments ----
  short8 xh[WT], xl[WT];
#pragma unroll
  for (int t = 0; t < WT; ++t) {
    const float* p = points + (size_t)(tileBase + t * 16 + col) * D + 8 * g;
    float4 a = *reinterpret_cast<const float4*>(p);
    float4 b = *reinterpret_cast<const float4*>(p + 4);
    float v[8] = {a.x, a.y, a.z, a.w, b.x, b.y, b.z, b.w};
    unsigned int hiu[8];
    unsigned int lou[8];
#pragma unroll
    for (int j = 0; j < 8; ++j) {
      unsigned int u = __float_as_uint(v[j]);
      hiu[j] = u & 0xFFFF0000u;  // exact split
      lou[j] = __float_as_uint(v[j] - __uint_as_float(hiu[j]));
    }
    union { short8 s; unsigned int w[4]; } H, Lo;
#pragma unroll
    for (int jj = 0; jj < 4; ++jj) {
      H.w[jj]  = __builtin_amdgcn_perm(hiu[2 * jj + 1], hiu[2 * jj], 0x07060302);
      Lo.w[jj] = __builtin_amdgcn_perm(lou[2 * jj + 1], lou[2 * jj], 0x07060302);
    }
    xh[t] = H.s;
    xl[t] = Lo.s;
  }

  float result[WT];
#pragma unroll
  for (int t = 0; t < WT; ++t) result[t] = 0.f;

  const short8* bh_base = reinterpret_cast<const short8*>(LH);
  const short8* bl_base = reinterpret_cast<const short8*>(LL);

#pragma unroll 4
  for (int m = 0; m < M; ++m) {
    short8 bh0 = bh_base[(m * 2 + 0) * 64 + lane];
    short8 bh1 = bh_base[(m * 2 + 1) * 64 + lane];
    short8 bl0 = bl_base[(m * 2 + 0) * 64 + lane];
    short8 bl1 = bl_base[(m * 2 + 1) * 64 + lane];
    const float2 cn = CN[m * 64 + lane];
    const float lc = LC[m];  // wave-uniform -> s_load

#pragma unroll
    for (int t = 0; t < WT; ++t) {
      f32x4 acc0 = (f32x4){cn.x, cn.x, cn.x, cn.x};  // z = (sL)^T x - (sL)^T c
      f32x4 acc1 = (f32x4){cn.y, cn.y, cn.y, cn.y};
      acc0 = __builtin_amdgcn_mfma_f32_16x16x32_bf16(xh[t], bh0, acc0, 0, 0, 0);
      acc0 = __builtin_amdgcn_mfma_f32_16x16x32_bf16(xl[t], bh0, acc0, 0, 0, 0);
      acc0 = __builtin_amdgcn_mfma_f32_16x16x32_bf16(xh[t], bl0, acc0, 0, 0, 0);
      acc1 = __builtin_amdgcn_mfma_f32_16x16x32_bf16(xh[t], bh1, acc1, 0, 0, 0);
      acc1 = __builtin_amdgcn_mfma_f32_16x16x32_bf16(xl[t], bh1, acc1, 0, 0, 0);
      acc1 = __builtin_amdgcn_mfma_f32_16x16x32_bf16(xh[t], bl1, acc1, 0, 0, 0);

      // s[r] = sum_k z_k^2 partials: 2 ror-add steps -> coset(lane&3) partial per r
      float sq0, sq1, sq2, sq3;
      {
        float s0 = fmaf(acc0[0], acc0[0], acc1[0] * acc1[0]);
        float s1 = fmaf(acc0[1], acc0[1], acc1[1] * acc1[1]);
        float s2 = fmaf(acc0[2], acc0[2], acc1[2] * acc1[2]);
        float s3 = fmaf(acc0[3], acc0[3], acc1[3] * acc1[3]);
        s0 = DPP_ADD(s0, 0x128); s0 = DPP_ADD(s0, 0x124);
        s1 = DPP_ADD(s1, 0x128); s1 = DPP_ADD(s1, 0x124);
        s2 = DPP_ADD(s2, 0x128); s2 = DPP_ADD(s2, 0x124);
        s3 = DPP_ADD(s3, 0x128); s3 = DPP_ADD(s3, 0x124);
        sq0 = s0; sq1 = s1; sq2 = s2; sq3 = s3;
      }
      // lane-transpose: lane i picks r = (i>>2)&3 (keeps its own coset i&3)
      float v = b1 ? (b0 ? sq3 : sq2) : (b0 ? sq1 : sq0);
      // quad butterfly: all 4 lanes of quad q get full dist(r=q), any direction
      v = DPP_ADD(v, 0xB1);
      v = DPP_ADD(v, 0x4E);
      // one exp2 per (m,t): coef*exp(-dist) = 2^(lc - dist_log2)
      result[t] += exp2f(lc - v);
    }
  }

  // lane 16g+4q (j==0) holds result for point t*16 + 4g + q
  if ((lane & 3) == 0) {
    const int q = (lane >> 2) & 3;
#pragma unroll
    for (int t = 0; t < WT; ++t)
      out[tileBase + t * 16 + 4 * g + q] = result[t];
  }
}

extern "C" void kernel_launch(void* const* d_in, const int* in_sizes, int n_in,
                              void* d_out, int out_size, void* d_ws, size_t ws_size,
                              hipStream_t stream) {
  const float* points  = (const float*)d_in[0];
  const float* centers = (const float*)d_in[1];
  const float* L       = (const float*)d_in[2];
  const float* weights = (const float*)d_in[3];
  float* out = (float*)d_out;
  const int N = in_sizes[0] / D;

  char* ws = (char*)d_ws;
  float2* CN          = (float2*)ws;                   // 32*64*8   = 16384 B
  float* LC           = (float*)(ws + 16384);          // 128 B
  unsigned short* LHf = (unsigned short*)(ws + 32768); // 65536 B
  unsigned short* LLf = (unsigned short*)(ws + 98304); // 65536 B

  gmm_pre<<<M, 64, 0, stream>>>(centers, L, weights, CN, LC, LHf, LLf);

  const int ptsPerBlock = 4 * WT * 16;  // 128 points per 256-thread block
  gmm_main<<<(N + ptsPerBlock - 1) / ptsPerBlock, 256, 0, stream>>>(
      points, CN, LC, LHf, LLf, out, N);
}

// Round 7
// 119.814 us; speedup vs baseline: 3.0083x; 1.0187x over previous
//
#include <hip/hip_runtime.h>
#include <hip/hip_bf16.h>

// out[n] = sum_m coefs[m] * exp(-||L_m^T (x_n - c_m)||^2),  coefs[m]=softmax(w)[m]*|det L_m|
// N=131072, M=32, D=32, f32.
//
// Round 4 (3rd resubmit after GPUAcquisitionTimeout x3): same math as round 3 (3x bf16
// Dekker-split MFMAs, log2-domain single exp2, DPP coset reduction). Structural
// change: B-fragment tables (128 KB) + bias table (4 KB) staged in LDS once per
// 1024-thread block (132 KB static __shared__, 1 block/CU, 4 waves/SIMD). Kills
// the per-m L2 re-read (~72 KB/CU/m) that made rounds 2/3 L2-BW-bound (~40 us);
// per-m reads are now conflict-free ds_read_b128.

#define D 32
#define M 32
#define WT 2  // point-tiles (of 16) per wave

typedef __attribute__((ext_vector_type(8))) short short8;
typedef __attribute__((ext_vector_type(4))) float f32x4;

__device__ __forceinline__ unsigned short f2bf_rne(float f) {
  unsigned int u = __float_as_uint(f);
  return (unsigned short)((u + 0x7FFFu + ((u >> 16) & 1u)) >> 16);
}

// x + dpp(x); 0x128=row_ror:8 0x124=row_ror:4 (coset sums: direction-invariant)
// 0xB1=quad_perm[1,0,3,2] 0x4E=quad_perm[2,3,0,1]
#define DPP_ADD(x, ctrl) \
  ((x) + __int_as_float(__builtin_amdgcn_mov_dpp(__float_as_int(x), (ctrl), 0xf, 0xf, true)))

#define SCL 1.2011224087864498f  // sqrt(log2(e))

__global__ __launch_bounds__(64) void gmm_pre(
    const float* __restrict__ centers, const float* __restrict__ L,
    const float* __restrict__ weights,
    float2* __restrict__ CNp, float* __restrict__ LC,
    unsigned short* __restrict__ LH, unsigned short* __restrict__ LL) {
  __shared__ float U[D][D + 1];
  __shared__ float C2s[D];
  const int m = blockIdx.x;
  const int t = threadIdx.x;
  const float* Lm = L + m * (D * D);

  if (t < D) {
    for (int k = 0; k < D; ++k) U[t][k] = Lm[t * D + k];
    float acc = 0.f;
    for (int d = 0; d < D; ++d) acc = fmaf(centers[m * D + d], Lm[d * D + t], acc);
    C2s[t] = acc;  // (L^T c)_t, unscaled
  }

  // B-fragment split of (SCL * L), layout [m][ktile][lane][j]
  {
    const int col = t & 15;
    const int dbase = 8 * (t >> 4);
    for (int kt = 0; kt < 2; ++kt) {
      for (int j = 0; j < 8; ++j) {
        const int d = dbase + j;
        const int k = kt * 16 + col;
        float v = Lm[d * D + k] * SCL;
        unsigned int hi = __float_as_uint(v) & 0xFFFF0000u;
        float lo = v - __uint_as_float(hi);
        size_t off = (((size_t)(m * 2 + kt)) * 64 + t) * 8 + j;
        LH[off] = (unsigned short)(hi >> 16);
        LL[off] = f2bf_rne(lo);
      }
    }
  }
  __syncthreads();

  // bias pair table: CNp[m][col] = (-(sL)^T c [col], -(sL)^T c [col+16])
  if (t < 16) CNp[m * 16 + t] = make_float2(-SCL * C2s[t], -SCL * C2s[16 + t]);

  // LU (no pivot; L ~ I + 0.05*noise) for |det|
  for (int p = 0; p < D - 1; ++p) {
    if (t > p && t < D) {
      float f = U[t][p] / U[p][p];
      for (int k = p; k < D; ++k) U[t][k] -= f * U[p][k];
    }
    __syncthreads();
  }
  if (t == 0) {
    float det = 1.f;
    for (int i = 0; i < D; ++i) det *= U[i][i];
    float mx = -1e30f;
    for (int j = 0; j < M; ++j) mx = fmaxf(mx, weights[j]);
    float s = 0.f;
    for (int j = 0; j < M; ++j) s += __expf(weights[j] - mx);
    float coef = (__expf(weights[m] - mx) / s) * fabsf(det);
    LC[m] = log2f(coef);
  }
}

__global__ __launch_bounds__(1024, 4) void gmm_main(
    const float* __restrict__ points,
    const float2* __restrict__ CNp, const float* __restrict__ LC,
    const unsigned short* __restrict__ LH, const unsigned short* __restrict__ LL,
    float* __restrict__ out, int N) {
  // 132 KB LDS: whole fragment + bias tables resident per CU
  __shared__ unsigned short sLH[M * 2 * 64 * 8];  // 64 KB
  __shared__ unsigned short sLL[M * 2 * 64 * 8];  // 64 KB
  __shared__ float2 sCN[M * 16];                  // 4 KB

  const int tid = threadIdx.x;
  const int lane = tid & 63;
  const int wave = tid >> 6;  // 0..15
  const int col = lane & 15;  // A-row (point) / B-col (k)
  const int g = lane >> 4;    // A k-slot base 8g; D rows 4g..4g+3

  // ---- one-time stage: 128 KB fragments + 4 KB bias into LDS ----
  {
    const uint4* src = reinterpret_cast<const uint4*>(LH);
    uint4* dst = reinterpret_cast<uint4*>(sLH);
#pragma unroll
    for (int i = 0; i < 4; ++i) dst[tid + i * 1024] = src[tid + i * 1024];
    src = reinterpret_cast<const uint4*>(LL);
    dst = reinterpret_cast<uint4*>(sLL);
#pragma unroll
    for (int i = 0; i < 4; ++i) dst[tid + i * 1024] = src[tid + i * 1024];
    if (tid < M * 16) sCN[tid] = CNp[tid];
  }

  const int tileBase = (blockIdx.x * 16 + wave) * (WT * 16);

  // lane-transpose selectors: lane i keeps coset i&3, picks r=(i>>2)&3
  const bool b0 = (lane >> 2) & 1;
  const bool b1 = (lane >> 2) & 2;

  // ---- load X tiles, Dekker-split into bf16 hi/lo fragments ----
  short8 xh[WT], xl[WT];
#pragma unroll
  for (int t = 0; t < WT; ++t) {
    const float* p = points + (size_t)(tileBase + t * 16 + col) * D + 8 * g;
    float4 a = *reinterpret_cast<const float4*>(p);
    float4 b = *reinterpret_cast<const float4*>(p + 4);
    float v[8] = {a.x, a.y, a.z, a.w, b.x, b.y, b.z, b.w};
    unsigned int hiu[8];
    unsigned int lou[8];
#pragma unroll
    for (int j = 0; j < 8; ++j) {
      unsigned int u = __float_as_uint(v[j]);
      hiu[j] = u & 0xFFFF0000u;  // exact split
      lou[j] = __float_as_uint(v[j] - __uint_as_float(hiu[j]));
    }
    union { short8 s; unsigned int w[4]; } H, Lo;
#pragma unroll
    for (int jj = 0; jj < 4; ++jj) {
      H.w[jj]  = __builtin_amdgcn_perm(hiu[2 * jj + 1], hiu[2 * jj], 0x07060302);
      Lo.w[jj] = __builtin_amdgcn_perm(lou[2 * jj + 1], lou[2 * jj], 0x07060302);
    }
    xh[t] = H.s;
    xl[t] = Lo.s;
  }

  __syncthreads();  // LDS tables ready

  float result[WT];
#pragma unroll
  for (int t = 0; t < WT; ++t) result[t] = 0.f;

  const short8* bh_base = reinterpret_cast<const short8*>(sLH);
  const short8* bl_base = reinterpret_cast<const short8*>(sLL);

#pragma unroll 2
  for (int m = 0; m < M; ++m) {
    short8 bh0 = bh_base[(m * 2 + 0) * 64 + lane];   // ds_read_b128, conflict-free
    short8 bh1 = bh_base[(m * 2 + 1) * 64 + lane];
    short8 bl0 = bl_base[(m * 2 + 0) * 64 + lane];
    short8 bl1 = bl_base[(m * 2 + 1) * 64 + lane];
    const float2 cn = sCN[m * 16 + col];             // ds_read_b64, bcast/conflict-free
    const float lc = LC[m];                          // wave-uniform -> s_load

#pragma unroll
    for (int t = 0; t < WT; ++t) {
      f32x4 acc0 = (f32x4){cn.x, cn.x, cn.x, cn.x};  // z = (sL)^T x - (sL)^T c
      f32x4 acc1 = (f32x4){cn.y, cn.y, cn.y, cn.y};
      acc0 = __builtin_amdgcn_mfma_f32_16x16x32_bf16(xh[t], bh0, acc0, 0, 0, 0);
      acc0 = __builtin_amdgcn_mfma_f32_16x16x32_bf16(xl[t], bh0, acc0, 0, 0, 0);
      acc0 = __builtin_amdgcn_mfma_f32_16x16x32_bf16(xh[t], bl0, acc0, 0, 0, 0);
      acc1 = __builtin_amdgcn_mfma_f32_16x16x32_bf16(xh[t], bh1, acc1, 0, 0, 0);
      acc1 = __builtin_amdgcn_mfma_f32_16x16x32_bf16(xl[t], bh1, acc1, 0, 0, 0);
      acc1 = __builtin_amdgcn_mfma_f32_16x16x32_bf16(xh[t], bl1, acc1, 0, 0, 0);

      // coset partials: 2 ror-adds per r
      float s0 = fmaf(acc0[0], acc0[0], acc1[0] * acc1[0]);
      float s1 = fmaf(acc0[1], acc0[1], acc1[1] * acc1[1]);
      float s2 = fmaf(acc0[2], acc0[2], acc1[2] * acc1[2]);
      float s3 = fmaf(acc0[3], acc0[3], acc1[3] * acc1[3]);
      s0 = DPP_ADD(s0, 0x128); s0 = DPP_ADD(s0, 0x124);
      s1 = DPP_ADD(s1, 0x128); s1 = DPP_ADD(s1, 0x124);
      s2 = DPP_ADD(s2, 0x128); s2 = DPP_ADD(s2, 0x124);
      s3 = DPP_ADD(s3, 0x128); s3 = DPP_ADD(s3, 0x124);
      // lane-transpose + quad butterfly -> full dist per quad
      float v = b1 ? (b0 ? s3 : s2) : (b0 ? s1 : s0);
      v = DPP_ADD(v, 0xB1);
      v = DPP_ADD(v, 0x4E);
      result[t] += exp2f(lc - v);  // coef*exp(-dist) = 2^(lc - dist_log2)
    }
  }

  // lane 16g+4q (j==0) holds result for point t*16 + 4g + q
  if ((lane & 3) == 0) {
    const int q = (lane >> 2) & 3;
#pragma unroll
    for (int t = 0; t < WT; ++t)
      out[tileBase + t * 16 + 4 * g + q] = result[t];
  }
}

extern "C" void kernel_launch(void* const* d_in, const int* in_sizes, int n_in,
                              void* d_out, int out_size, void* d_ws, size_t ws_size,
                              hipStream_t stream) {
  const float* points  = (const float*)d_in[0];
  const float* centers = (const float*)d_in[1];
  const float* L       = (const float*)d_in[2];
  const float* weights = (const float*)d_in[3];
  float* out = (float*)d_out;
  const int N = in_sizes[0] / D;

  char* ws = (char*)d_ws;
  float2* CNp         = (float2*)ws;                    // 32*16*8 = 4096 B
  float* LC           = (float*)(ws + 4096);            // 128 B
  unsigned short* LHf = (unsigned short*)(ws + 8192);   // 65536 B
  unsigned short* LLf = (unsigned short*)(ws + 8192 + 65536);

  gmm_pre<<<M, 64, 0, stream>>>(centers, L, weights, CNp, LC, LHf, LLf);

  // 1024 threads = 16 waves; 512 points per block; grid = 256 = 1 block/CU
  gmm_main<<<N / (16 * WT * 16), 1024, 0, stream>>>(
      points, CNp, LC, LHf, LLf, out, N);
}